// Round 3
// baseline (11200.768 us; speedup 1.0000x reference)
//
#include <hip/hip_runtime.h>
#include <hip/hip_bf16.h>
#include <math.h>

// Problem constants (B=1 throughout)
constexpr int SQ = 2048, SK = 3072, TT = 4096, DM = 2048;
constexpr int H = 16, HKV = 8, D = 128, FF = 6144;
#define EPS 1e-6f

// ---------------------------------------------------------------------------
// RMSNorm over rows of `ncols` (block = 256 threads, grid = nrows). f32 I/O.
// ---------------------------------------------------------------------------
__global__ __launch_bounds__(256) void rmsnorm_kernel(
    const float* __restrict__ x, const float* __restrict__ w,
    float* __restrict__ y, int ncols) {
  int row = blockIdx.x;
  const float* xr = x + (size_t)row * ncols;
  float* yr = y + (size_t)row * ncols;
  float ss = 0.f;
  for (int c = threadIdx.x; c < ncols; c += 256) { float v = xr[c]; ss += v * v; }
  for (int o = 32; o > 0; o >>= 1) ss += __shfl_down(ss, o);
  __shared__ float sred[4];
  int lane = threadIdx.x & 63, wid = threadIdx.x >> 6;
  if (lane == 0) sred[wid] = ss;
  __syncthreads();
  if (threadIdx.x == 0) {
    float t = sred[0] + sred[1] + sred[2] + sred[3];
    sred[0] = rsqrtf(t / (float)ncols + EPS);
  }
  __syncthreads();
  float scale = sred[0];
  for (int c = threadIdx.x; c < ncols; c += 256) yr[c] = xr[c] * scale * w[c];
}

// ---------------------------------------------------------------------------
// Tiled f32 GEMM: C[M,N] = A[M,K] @ B[K,N] (+ Add[M,N] if ADD)
// 64x64 tile, BK=16, 256 threads, 4x4 per-thread accum. Dims all %64/%16==0.
// ---------------------------------------------------------------------------
template <bool ADD>
__global__ __launch_bounds__(256) void gemm_kernel(
    const float* __restrict__ A, const float* __restrict__ Bm,
    const float* __restrict__ Add, float* __restrict__ C,
    int M, int N, int K) {
  __shared__ float As[64][17];   // [m][k], +1 pad
  __shared__ float Bs[16][65];   // [k][n], +1 pad
  int tid = threadIdx.x;
  int bm = blockIdx.y * 64, bn = blockIdx.x * 64;
  float acc[4][4] = {};
  int tx = tid & 15, ty = tid >> 4;
  for (int k0 = 0; k0 < K; k0 += 16) {
    {
      int c = tid & 15, r0 = tid >> 4;
#pragma unroll
      for (int p = 0; p < 4; p++) {
        int r = r0 + p * 16;
        As[r][c] = A[(size_t)(bm + r) * K + k0 + c];
      }
    }
    {
      int c = tid & 63, r0 = tid >> 6;
#pragma unroll
      for (int p = 0; p < 4; p++) {
        int r = r0 + p * 4;
        Bs[r][c] = Bm[(size_t)(k0 + r) * N + bn + c];
      }
    }
    __syncthreads();
#pragma unroll
    for (int kk = 0; kk < 16; kk++) {
      float a[4], b[4];
#pragma unroll
      for (int i = 0; i < 4; i++) a[i] = As[ty * 4 + i][kk];
#pragma unroll
      for (int j = 0; j < 4; j++) b[j] = Bs[kk][tx * 4 + j];
#pragma unroll
      for (int i = 0; i < 4; i++)
#pragma unroll
        for (int j = 0; j < 4; j++) acc[i][j] += a[i] * b[j];
    }
    __syncthreads();
  }
#pragma unroll
  for (int i = 0; i < 4; i++)
#pragma unroll
    for (int j = 0; j < 4; j++) {
      size_t idx = (size_t)(bm + ty * 4 + i) * N + bn + tx * 4 + j;
      C[idx] = ADD ? (acc[i][j] + Add[idx]) : acc[i][j];
    }
}

// ---------------------------------------------------------------------------
// Per-head RMSNorm (over D=128) + RoPE, in place.
// x layout: [S][nheads][D]. grid = (S, nheads), block = 128.
// ---------------------------------------------------------------------------
__global__ __launch_bounds__(128) void qknorm_rope_kernel(
    float* __restrict__ x, const float* __restrict__ nw,
    const int* __restrict__ pos, int nheads) {
  int s = blockIdx.x, hh = blockIdx.y;
  float* xr = x + ((size_t)s * nheads + hh) * D;
  int d = threadIdx.x;
  float vv = xr[d];
  float ss = vv * vv;
  for (int o = 32; o > 0; o >>= 1) ss += __shfl_down(ss, o);
  __shared__ float sred[2];
  __shared__ float sn[D];
  if ((d & 63) == 0) sred[d >> 6] = ss;
  __syncthreads();
  float ms = (sred[0] + sred[1]) * (1.0f / (float)D);
  float n = vv * rsqrtf(ms + EPS) * nw[d];
  sn[d] = n;
  __syncthreads();
  int t = d & 63;
  float inv = powf(1000000.0f, -((float)(2 * t)) / (float)D);
  float ang = (float)pos[s] * inv;
  float c = cosf(ang), si = sinf(ang);
  float rh = (d < 64) ? -sn[d + 64] : sn[d - 64];
  xr[d] = n * c + rh * si;
}

// ---------------------------------------------------------------------------
// Flash-style GQA attention. grid = (SQ, H), block = 256 (4 waves).
// q: [SQ][H][D], k/v: [SK][HKV][D], mask f32 [TT][TT], ctx: [SQ][H*D]
// ---------------------------------------------------------------------------
__global__ __launch_bounds__(256) void attn_kernel(
    const float* __restrict__ q, const float* __restrict__ k,
    const float* __restrict__ v, const float* __restrict__ mask,
    const int* __restrict__ hs_idxs, const int* __restrict__ key_idxs,
    float* __restrict__ ctx) {
  int qi = blockIdx.x, hh = blockIdx.y;
  int kvh = hh >> 1;  // H/HKV == 2
  const float scale = 0.08838834764831845f;  // 128^-0.5
  __shared__ float qs[D];
  __shared__ float sm[4], sl[4], sacc[4][D];
  int tid = threadIdx.x;
  if (tid < D) qs[tid] = q[((size_t)qi * H + hh) * D + tid];
  __syncthreads();
  int lane = tid & 63, wid = tid >> 6;
  const float* maskrow = mask + (size_t)hs_idxs[qi] * TT;
  float m = -INFINITY, l = 0.f, a0 = 0.f, a1 = 0.f;
  float q0 = qs[lane], q1 = qs[lane + 64];
  for (int j = wid; j < SK; j += 4) {
    const float* kr = k + ((size_t)j * HKV + kvh) * D;
    float p = q0 * kr[lane] + q1 * kr[lane + 64];
#pragma unroll
    for (int o = 1; o < 64; o <<= 1) p += __shfl_xor(p, o);
    float s = p * scale + maskrow[key_idxs[j]];
    float mn = fmaxf(m, s);
    float f = __expf(m - mn);
    float pe = __expf(s - mn);
    m = mn;
    l = l * f + pe;
    const float* vr = v + ((size_t)j * HKV + kvh) * D;
    a0 = a0 * f + pe * vr[lane];
    a1 = a1 * f + pe * vr[lane + 64];
  }
  if (lane == 0) { sm[wid] = m; sl[wid] = l; }
  sacc[wid][lane] = a0;
  sacc[wid][lane + 64] = a1;
  __syncthreads();
  if (tid < D) {
    float mt = fmaxf(fmaxf(sm[0], sm[1]), fmaxf(sm[2], sm[3]));
    float lt = 0.f, at = 0.f;
#pragma unroll
    for (int w2 = 0; w2 < 4; w2++) {
      float f = __expf(sm[w2] - mt);
      lt += sl[w2] * f;
      at += sacc[w2][tid] * f;
    }
    ctx[((size_t)qi * H + hh) * D + tid] = at / lt;
  }
}

// ---------------------------------------------------------------------------
// gate = silu(gate) * up
// ---------------------------------------------------------------------------
__global__ __launch_bounds__(256) void silu_mul_kernel(
    float* __restrict__ g, const float* __restrict__ u, int n) {
  int i = blockIdx.x * 256 + threadIdx.x;
  if (i < n) {
    float x = g[i];
    g[i] = (x / (1.f + __expf(-x))) * u[i];
  }
}

// ---------------------------------------------------------------------------
// out_f32 = a + b   (output buffer is f32 — reference returns float32)
// ---------------------------------------------------------------------------
__global__ __launch_bounds__(256) void add_out_kernel(
    const float* __restrict__ a, const float* __restrict__ b,
    float* __restrict__ o, int n) {
  int i = blockIdx.x * 256 + threadIdx.x;
  if (i < n) o[i] = a[i] + b[i];
}

// ---------------------------------------------------------------------------
extern "C" void kernel_launch(void* const* d_in, const int* in_sizes, int n_in,
                              void* d_out, int out_size, void* d_ws, size_t ws_size,
                              hipStream_t stream) {
  (void)in_sizes; (void)n_in; (void)out_size; (void)ws_size;
  const float* hidden_states = (const float*)d_in[0];
  const float* kv_hidden     = (const float*)d_in[1];
  const float* causal_mask   = (const float*)d_in[2];
  const float* w_q      = (const float*)d_in[3];
  const float* w_k      = (const float*)d_in[4];
  const float* w_v      = (const float*)d_in[5];
  const float* w_o      = (const float*)d_in[6];
  const float* q_norm_w = (const float*)d_in[7];
  const float* k_norm_w = (const float*)d_in[8];
  const float* ln1_w    = (const float*)d_in[9];
  const float* ln2_w    = (const float*)d_in[10];
  const float* w_gate   = (const float*)d_in[11];
  const float* w_up     = (const float*)d_in[12];
  const float* w_down   = (const float*)d_in[13];
  const int* positions    = (const int*)d_in[14];
  const int* kv_positions = (const int*)d_in[15];
  const int* hs_idxs      = (const int*)d_in[16];
  const int* key_idxs     = (const int*)d_in[17];

  float* ws = (float*)d_ws;
  size_t off = 0;
  float* h      = ws + off; off += (size_t)SQ * DM;        // later: h2
  float* hk     = ws + off; off += (size_t)SK * DM;        // later: gate start
  float* qb     = ws + off; off += (size_t)SQ * H * D;
  float* kb     = ws + off; off += (size_t)SK * HKV * D;
  float* vb     = ws + off; off += (size_t)SK * HKV * D;
  float* ctxb   = ws + off; off += (size_t)SQ * H * D;     // later: mlpout
  float* hidden = ws + off; off += (size_t)SQ * DM;
  float* up     = ws + off; off += (size_t)SQ * FF;
  float* gate   = hk;      // overlays hk+qb+kb (13.6M >= 12.6M), dead by then
  float* h2     = h;       // h dead after q-proj
  float* mlpout = ctxb;    // ctx dead after o-proj

  // 1) input layernorm on both streams
  rmsnorm_kernel<<<SQ, 256, 0, stream>>>(hidden_states, ln1_w, h, DM);
  rmsnorm_kernel<<<SK, 256, 0, stream>>>(kv_hidden, ln1_w, hk, DM);

  // 2) q/k/v projections
  gemm_kernel<false><<<dim3((H * D) / 64, SQ / 64), 256, 0, stream>>>(
      h, w_q, nullptr, qb, SQ, H * D, DM);
  gemm_kernel<false><<<dim3((HKV * D) / 64, SK / 64), 256, 0, stream>>>(
      hk, w_k, nullptr, kb, SK, HKV * D, DM);
  gemm_kernel<false><<<dim3((HKV * D) / 64, SK / 64), 256, 0, stream>>>(
      hk, w_v, nullptr, vb, SK, HKV * D, DM);

  // 3) per-head q/k RMSNorm + RoPE (in place)
  qknorm_rope_kernel<<<dim3(SQ, H), 128, 0, stream>>>(qb, q_norm_w, positions, H);
  qknorm_rope_kernel<<<dim3(SK, HKV), 128, 0, stream>>>(kb, k_norm_w, kv_positions, HKV);

  // 4) attention (flash-style, no materialized scores)
  attn_kernel<<<dim3(SQ, H), 256, 0, stream>>>(
      qb, kb, vb, causal_mask, hs_idxs, key_idxs, ctxb);

  // 5) o-proj + residual
  gemm_kernel<true><<<dim3(DM / 64, SQ / 64), 256, 0, stream>>>(
      ctxb, w_o, hidden_states, hidden, SQ, DM, H * D);

  // 6) post-attn norm + SwiGLU MLP
  rmsnorm_kernel<<<SQ, 256, 0, stream>>>(hidden, ln2_w, h2, DM);
  gemm_kernel<false><<<dim3(FF / 64, SQ / 64), 256, 0, stream>>>(
      h2, w_gate, nullptr, gate, SQ, FF, DM);
  gemm_kernel<false><<<dim3(FF / 64, SQ / 64), 256, 0, stream>>>(
      h2, w_up, nullptr, up, SQ, FF, DM);
  silu_mul_kernel<<<(SQ * FF + 255) / 256, 256, 0, stream>>>(gate, up, SQ * FF);
  gemm_kernel<false><<<dim3(DM / 64, SQ / 64), 256, 0, stream>>>(
      gate, w_down, nullptr, mlpout, SQ, DM, FF);

  // 7) final residual (f32 output)
  add_out_kernel<<<(SQ * DM + 255) / 256, 256, 0, stream>>>(
      hidden, mlpout, (float*)d_out, SQ * DM);
}

// Round 4
// 5315.004 us; speedup vs baseline: 2.1074x; 2.1074x over previous
//
#include <hip/hip_runtime.h>
#include <hip/hip_bf16.h>
#include <math.h>

// Problem constants (B=1 throughout)
constexpr int SQ = 2048, SK = 3072, TT = 4096, DM = 2048;
constexpr int H = 16, HKV = 8, D = 128, FF = 6144;
#define EPS 1e-6f

__device__ __forceinline__ unsigned short f2bf(float f) {
  unsigned u = __float_as_uint(f);
  unsigned r = (u + 0x7fffu + ((u >> 16) & 1u)) >> 16;
  return (unsigned short)r;
}
__device__ __forceinline__ float bflo(unsigned w) { return __uint_as_float(w << 16); }
__device__ __forceinline__ float bfhi(unsigned w) { return __uint_as_float(w & 0xffff0000u); }

// ---------------------------------------------------------------------------
// RMSNorm over rows of `ncols` (block = 256 threads, grid = nrows). f32 I/O.
// ---------------------------------------------------------------------------
__global__ __launch_bounds__(256) void rmsnorm_kernel(
    const float* __restrict__ x, const float* __restrict__ w,
    float* __restrict__ y, int ncols) {
  int row = blockIdx.x;
  const float* xr = x + (size_t)row * ncols;
  float* yr = y + (size_t)row * ncols;
  float ss = 0.f;
  for (int c = threadIdx.x; c < ncols; c += 256) { float v = xr[c]; ss += v * v; }
  for (int o = 32; o > 0; o >>= 1) ss += __shfl_down(ss, o);
  __shared__ float sred[4];
  int lane = threadIdx.x & 63, wid = threadIdx.x >> 6;
  if (lane == 0) sred[wid] = ss;
  __syncthreads();
  if (threadIdx.x == 0) {
    float t = sred[0] + sred[1] + sred[2] + sred[3];
    sred[0] = rsqrtf(t / (float)ncols + EPS);
  }
  __syncthreads();
  float scale = sred[0];
  for (int c = threadIdx.x; c < ncols; c += 256) yr[c] = xr[c] * scale * w[c];
}

// ---------------------------------------------------------------------------
// Tiled f32 GEMM: C[M,N] = A[M,K] @ B[K,N] (+ Add[M,N] if ADD)
// ---------------------------------------------------------------------------
template <bool ADD>
__global__ __launch_bounds__(256) void gemm_kernel(
    const float* __restrict__ A, const float* __restrict__ Bm,
    const float* __restrict__ Add, float* __restrict__ C,
    int M, int N, int K) {
  __shared__ float As[64][17];
  __shared__ float Bs[16][65];
  int tid = threadIdx.x;
  int bm = blockIdx.y * 64, bn = blockIdx.x * 64;
  float acc[4][4] = {};
  int tx = tid & 15, ty = tid >> 4;
  for (int k0 = 0; k0 < K; k0 += 16) {
    {
      int c = tid & 15, r0 = tid >> 4;
#pragma unroll
      for (int p = 0; p < 4; p++) {
        int r = r0 + p * 16;
        As[r][c] = A[(size_t)(bm + r) * K + k0 + c];
      }
    }
    {
      int c = tid & 63, r0 = tid >> 6;
#pragma unroll
      for (int p = 0; p < 4; p++) {
        int r = r0 + p * 4;
        Bs[r][c] = Bm[(size_t)(k0 + r) * N + bn + c];
      }
    }
    __syncthreads();
#pragma unroll
    for (int kk = 0; kk < 16; kk++) {
      float a[4], b[4];
#pragma unroll
      for (int i = 0; i < 4; i++) a[i] = As[ty * 4 + i][kk];
#pragma unroll
      for (int j = 0; j < 4; j++) b[j] = Bs[kk][tx * 4 + j];
#pragma unroll
      for (int i = 0; i < 4; i++)
#pragma unroll
        for (int j = 0; j < 4; j++) acc[i][j] += a[i] * b[j];
    }
    __syncthreads();
  }
#pragma unroll
  for (int i = 0; i < 4; i++)
#pragma unroll
    for (int j = 0; j < 4; j++) {
      size_t idx = (size_t)(bm + ty * 4 + i) * N + bn + tx * 4 + j;
      C[idx] = ADD ? (acc[i][j] + Add[idx]) : acc[i][j];
    }
}

// ---------------------------------------------------------------------------
// Per-head RMSNorm (over D=128) + RoPE, in place.
// ---------------------------------------------------------------------------
__global__ __launch_bounds__(128) void qknorm_rope_kernel(
    float* __restrict__ x, const float* __restrict__ nw,
    const int* __restrict__ pos, int nheads) {
  int s = blockIdx.x, hh = blockIdx.y;
  float* xr = x + ((size_t)s * nheads + hh) * D;
  int d = threadIdx.x;
  float vv = xr[d];
  float ss = vv * vv;
  for (int o = 32; o > 0; o >>= 1) ss += __shfl_down(ss, o);
  __shared__ float sred[2];
  __shared__ float sn[D];
  if ((d & 63) == 0) sred[d >> 6] = ss;
  __syncthreads();
  float ms = (sred[0] + sred[1]) * (1.0f / (float)D);
  float n = vv * rsqrtf(ms + EPS) * nw[d];
  sn[d] = n;
  __syncthreads();
  int t = d & 63;
  float inv = powf(1000000.0f, -((float)(2 * t)) / (float)D);
  float ang = (float)pos[s] * inv;
  float c = cosf(ang), si = sinf(ang);
  float rh = (d < 64) ? -sn[d + 64] : sn[d - 64];
  xr[d] = n * c + rh * si;
}

// ---------------------------------------------------------------------------
// Pre-gather mask: maskg[q][j] = mask[hs_idxs[q]*TT + key_idxs[j]]
// grid = SQ, block = 256
// ---------------------------------------------------------------------------
__global__ __launch_bounds__(256) void mask_gather_kernel(
    const float* __restrict__ mask, const int* __restrict__ hs_idxs,
    const int* __restrict__ key_idxs, float* __restrict__ maskg) {
  int q = blockIdx.x;
  const float* base = mask + (size_t)hs_idxs[q] * TT;
  float* out = maskg + (size_t)q * SK;
  for (int j = threadIdx.x; j < SK; j += 256) out[j] = base[key_idxs[j]];
}

// ---------------------------------------------------------------------------
// Tiled flash attention, bf16-in-LDS, f32 accum. grid = (SQ/64, H), block 256.
// q: [SQ][H][D], k/v: [SK][HKV][D] (f32), maskg: [SQ][SK], ctx: [SQ][H*D]
// LDS word-stride 65 => bank = (row + col) % 32, <=2-way everywhere.
// ---------------------------------------------------------------------------
__global__ __launch_bounds__(256) void attn_kernel(
    const float* __restrict__ q, const float* __restrict__ k,
    const float* __restrict__ v, const float* __restrict__ maskg,
    float* __restrict__ ctx) {
  __shared__ unsigned QsU[64 * 65];
  __shared__ unsigned KsU[64 * 65];   // reused as f32 Sg[64][65] in PV phase
  __shared__ unsigned VsU[64 * 65];
  float* Sg = (float*)KsU;

  const int tid = threadIdx.x;
  const int tx = tid & 15, ty = tid >> 4;
  const int qblk = blockIdx.x * 64;
  const int hh = blockIdx.y;
  const int kvh = hh >> 1;  // H/HKV == 2
  const float scale = 0.08838834764831845f;  // 128^-0.5

  const int srow = tid >> 5;   // 0..7 (staging row within round)
  const int d4 = tid & 31;     // float4 column index 0..31

  // ---- stage Q tile once (bf16-packed) ----
#pragma unroll
  for (int i = 0; i < 8; i++) {
    int r = i * 8 + srow;
    const float4 f = *(const float4*)&q[(((size_t)(qblk + r)) * H + hh) * D + 4 * d4];
    QsU[r * 65 + 2 * d4]     = ((unsigned)f2bf(f.y) << 16) | f2bf(f.x);
    QsU[r * 65 + 2 * d4 + 1] = ((unsigned)f2bf(f.w) << 16) | f2bf(f.z);
  }

  float m_i[4], l_i[4], o[4][8];
#pragma unroll
  for (int i = 0; i < 4; i++) {
    m_i[i] = -INFINITY; l_i[i] = 0.f;
#pragma unroll
    for (int c = 0; c < 8; c++) o[i][c] = 0.f;
  }

  for (int j0 = 0; j0 < SK; j0 += 64) {
    __syncthreads();  // prev PV done reading Sg/Vs
    // ---- stage K,V tiles (bf16-packed) ----
#pragma unroll
    for (int i = 0; i < 8; i++) {
      int r = i * 8 + srow;
      size_t gbase = (((size_t)(j0 + r)) * HKV + kvh) * D + 4 * d4;
      const float4 fk = *(const float4*)&k[gbase];
      KsU[r * 65 + 2 * d4]     = ((unsigned)f2bf(fk.y) << 16) | f2bf(fk.x);
      KsU[r * 65 + 2 * d4 + 1] = ((unsigned)f2bf(fk.w) << 16) | f2bf(fk.z);
      const float4 fv = *(const float4*)&v[gbase];
      VsU[r * 65 + 2 * d4]     = ((unsigned)f2bf(fv.y) << 16) | f2bf(fv.x);
      VsU[r * 65 + 2 * d4 + 1] = ((unsigned)f2bf(fv.w) << 16) | f2bf(fv.z);
    }
    // prefetch mask values (hide latency under S compute)
    float mk[4][4];
#pragma unroll
    for (int i = 0; i < 4; i++)
#pragma unroll
      for (int j = 0; j < 4; j++)
        mk[i][j] = maskg[(size_t)(qblk + 4 * ty + i) * SK + j0 + 4 * tx + j];
    __syncthreads();  // tiles staged

    // ---- S = Q K^T (bf16 pairs, f32 accum) ----
    float s[4][4] = {};
#pragma unroll 4
    for (int dp = 0; dp < 64; dp++) {
      unsigned qw[4], kw[4];
#pragma unroll
      for (int i = 0; i < 4; i++) qw[i] = QsU[(4 * ty + i) * 65 + dp];
#pragma unroll
      for (int j = 0; j < 4; j++) kw[j] = KsU[(4 * tx + j) * 65 + dp];
#pragma unroll
      for (int i = 0; i < 4; i++) {
        float ql = bflo(qw[i]), qh = bfhi(qw[i]);
#pragma unroll
        for (int j = 0; j < 4; j++) {
          s[i][j] += ql * bflo(kw[j]);
          s[i][j] += qh * bfhi(kw[j]);
        }
      }
    }
    __syncthreads();  // all Ks reads done (Sg will overwrite)

    // ---- online softmax (state replicated across the 16-lane tx group) ----
    float alpha[4];
#pragma unroll
    for (int i = 0; i < 4; i++) {
      float rm = s[i][0];
#pragma unroll
      for (int j = 0; j < 4; j++) {
        s[i][j] = s[i][j] * scale + mk[i][j];
        rm = fmaxf(rm, s[i][j]);
      }
      // redo max properly including scale+mask (first iteration seeded raw)
      rm = fmaxf(fmaxf(s[i][0], s[i][1]), fmaxf(s[i][2], s[i][3]));
#pragma unroll
      for (int off = 1; off < 16; off <<= 1) rm = fmaxf(rm, __shfl_xor(rm, off));
      float mn = fmaxf(m_i[i], rm);
      alpha[i] = __expf(m_i[i] - mn);
      float rs = 0.f;
#pragma unroll
      for (int j = 0; j < 4; j++) { s[i][j] = __expf(s[i][j] - mn); rs += s[i][j]; }
#pragma unroll
      for (int off = 1; off < 16; off <<= 1) rs += __shfl_xor(rs, off);
      l_i[i] = l_i[i] * alpha[i] + rs;
      m_i[i] = mn;
#pragma unroll
      for (int c = 0; c < 8; c++) o[i][c] *= alpha[i];
    }
    // write P to Sg
#pragma unroll
    for (int i = 0; i < 4; i++)
#pragma unroll
      for (int j = 0; j < 4; j++) Sg[(4 * ty + i) * 65 + 4 * tx + j] = s[i][j];
    __syncthreads();  // Sg ready

    // ---- O += P V ----
#pragma unroll 2
    for (int kk = 0; kk < 64; kk++) {
      float p[4];
#pragma unroll
      for (int i = 0; i < 4; i++) p[i] = Sg[(4 * ty + i) * 65 + kk];
      unsigned v0 = VsU[kk * 65 + 2 * tx];
      unsigned v1 = VsU[kk * 65 + 2 * tx + 1];
      unsigned v2 = VsU[kk * 65 + 32 + 2 * tx];
      unsigned v3 = VsU[kk * 65 + 32 + 2 * tx + 1];
      float vv[8] = { bflo(v0), bfhi(v0), bflo(v1), bfhi(v1),
                      bflo(v2), bfhi(v2), bflo(v3), bfhi(v3) };
#pragma unroll
      for (int i = 0; i < 4; i++)
#pragma unroll
        for (int c = 0; c < 8; c++) o[i][c] += p[i] * vv[c];
    }
  }

  // ---- epilogue: normalize and store ----
#pragma unroll
  for (int i = 0; i < 4; i++) {
    float inv = 1.f / l_i[i];
    float4 lo = make_float4(o[i][0] * inv, o[i][1] * inv, o[i][2] * inv, o[i][3] * inv);
    float4 hi = make_float4(o[i][4] * inv, o[i][5] * inv, o[i][6] * inv, o[i][7] * inv);
    size_t base = (((size_t)(qblk + 4 * ty + i)) * H + hh) * D;
    *(float4*)&ctx[base + 4 * tx] = lo;
    *(float4*)&ctx[base + 64 + 4 * tx] = hi;
  }
}

// ---------------------------------------------------------------------------
__global__ __launch_bounds__(256) void silu_mul_kernel(
    float* __restrict__ g, const float* __restrict__ u, int n) {
  int i = blockIdx.x * 256 + threadIdx.x;
  if (i < n) {
    float x = g[i];
    g[i] = (x / (1.f + __expf(-x))) * u[i];
  }
}

__global__ __launch_bounds__(256) void add_out_kernel(
    const float* __restrict__ a, const float* __restrict__ b,
    float* __restrict__ o, int n) {
  int i = blockIdx.x * 256 + threadIdx.x;
  if (i < n) o[i] = a[i] + b[i];
}

// ---------------------------------------------------------------------------
extern "C" void kernel_launch(void* const* d_in, const int* in_sizes, int n_in,
                              void* d_out, int out_size, void* d_ws, size_t ws_size,
                              hipStream_t stream) {
  (void)in_sizes; (void)n_in; (void)out_size; (void)ws_size;
  const float* hidden_states = (const float*)d_in[0];
  const float* kv_hidden     = (const float*)d_in[1];
  const float* causal_mask   = (const float*)d_in[2];
  const float* w_q      = (const float*)d_in[3];
  const float* w_k      = (const float*)d_in[4];
  const float* w_v      = (const float*)d_in[5];
  const float* w_o      = (const float*)d_in[6];
  const float* q_norm_w = (const float*)d_in[7];
  const float* k_norm_w = (const float*)d_in[8];
  const float* ln1_w    = (const float*)d_in[9];
  const float* ln2_w    = (const float*)d_in[10];
  const float* w_gate   = (const float*)d_in[11];
  const float* w_up     = (const float*)d_in[12];
  const float* w_down   = (const float*)d_in[13];
  const int* positions    = (const int*)d_in[14];
  const int* kv_positions = (const int*)d_in[15];
  const int* hs_idxs      = (const int*)d_in[16];
  const int* key_idxs     = (const int*)d_in[17];

  float* ws = (float*)d_ws;
  size_t off = 0;
  float* h      = ws + off; off += (size_t)SQ * DM;        // later: h2
  float* hk     = ws + off; off += (size_t)SK * DM;        // later: gate start
  float* qb     = ws + off; off += (size_t)SQ * H * D;
  float* kb     = ws + off; off += (size_t)SK * HKV * D;
  float* vb     = ws + off; off += (size_t)SK * HKV * D;
  float* ctxb   = ws + off; off += (size_t)SQ * H * D;     // later: mlpout
  float* hidden = ws + off; off += (size_t)SQ * DM;
  float* up     = ws + off; off += (size_t)SQ * FF;
  float* gate   = hk;      // overlays hk+qb+kb (13.6M >= 12.6M), dead by then
  float* h2     = h;       // h dead after q-proj
  float* mlpout = ctxb;    // ctx dead after o-proj
  float* maskg  = up;      // maskg (6.3M) lives before `up` (12.6M) is written

  // 0) pre-gather mask
  mask_gather_kernel<<<SQ, 256, 0, stream>>>(causal_mask, hs_idxs, key_idxs, maskg);

  // 1) input layernorm on both streams
  rmsnorm_kernel<<<SQ, 256, 0, stream>>>(hidden_states, ln1_w, h, DM);
  rmsnorm_kernel<<<SK, 256, 0, stream>>>(kv_hidden, ln1_w, hk, DM);

  // 2) q/k/v projections
  gemm_kernel<false><<<dim3((H * D) / 64, SQ / 64), 256, 0, stream>>>(
      h, w_q, nullptr, qb, SQ, H * D, DM);
  gemm_kernel<false><<<dim3((HKV * D) / 64, SK / 64), 256, 0, stream>>>(
      hk, w_k, nullptr, kb, SK, HKV * D, DM);
  gemm_kernel<false><<<dim3((HKV * D) / 64, SK / 64), 256, 0, stream>>>(
      hk, w_v, nullptr, vb, SK, HKV * D, DM);

  // 3) per-head q/k RMSNorm + RoPE (in place)
  qknorm_rope_kernel<<<dim3(SQ, H), 128, 0, stream>>>(qb, q_norm_w, positions, H);
  qknorm_rope_kernel<<<dim3(SK, HKV), 128, 0, stream>>>(kb, k_norm_w, kv_positions, HKV);

  // 4) attention (tiled flash, bf16 LDS)
  attn_kernel<<<dim3(SQ / 64, H), 256, 0, stream>>>(qb, kb, vb, maskg, ctxb);

  // 5) o-proj + residual
  gemm_kernel<true><<<dim3(DM / 64, SQ / 64), 256, 0, stream>>>(
      ctxb, w_o, hidden_states, hidden, SQ, DM, H * D);

  // 6) post-attn norm + SwiGLU MLP
  rmsnorm_kernel<<<SQ, 256, 0, stream>>>(hidden, ln2_w, h2, DM);
  gemm_kernel<false><<<dim3(FF / 64, SQ / 64), 256, 0, stream>>>(
      h2, w_gate, nullptr, gate, SQ, FF, DM);
  gemm_kernel<false><<<dim3(FF / 64, SQ / 64), 256, 0, stream>>>(
      h2, w_up, nullptr, up, SQ, FF, DM);
  silu_mul_kernel<<<(SQ * FF + 255) / 256, 256, 0, stream>>>(gate, up, SQ * FF);
  gemm_kernel<false><<<dim3(DM / 64, SQ / 64), 256, 0, stream>>>(
      gate, w_down, nullptr, mlpout, SQ, DM, FF);

  // 7) final residual (f32 output)
  add_out_kernel<<<(SQ * DM + 255) / 256, 256, 0, stream>>>(
      hidden, mlpout, (float*)d_out, SQ * DM);
}